// Round 15
// baseline (108.919 us; speedup 1.0000x reference)
//
#include <hip/hip_runtime.h>
#include <cstddef>

#define NT 10            // NUM_TOKENS
#define TD 96            // TOKEN_DIM == REF_DIM
#define NH 4             // NUM_HEADS
#define NPOS (32 * 2048) // B*T positions
#define TPB 256
#define LPP 8            // lanes per position
#define XPL 12           // x elems per lane (TD / LPP)

// workspace layout (bytes)
// wq2 packed swizzled Wq f16: [cc=12][i=8][l=8][6 h2] = 18432 B (no pad!).
//   element (cc,i,l,m) = pack(Wq[8cc+(l^i)][l*12+2m], Wq[8cc+(l^i)][l*12+2m+1])
#define WS_WQ2 0
#define WS_KVW 18432     // float kvw[96][16]: row d = [wv0..3 | kv0..9 | pad2] (6144 B)
#define WS_WVP 24576     // h2 wvp[6][8][4]: (Wv[h][16pp+l], Wv[h][16pp+8+l]) (768 B)
#define WS_BYTES 25344

typedef _Float16 h2 __attribute__((ext_vector_type(2)));

__device__ __forceinline__ h2 pack_h2(float a, float b) {
    return __builtin_bit_cast(h2, __builtin_amdgcn_cvt_pkrtz(a, b));
}

__device__ __forceinline__ float fast_tanh(float x) {
    // tanh(x) = 1 - 2/(exp(2x)+1); exact limits at +/-inf, ~1e-6 rel error
    float e = __expf(2.0f * x);
    return 1.0f - 2.0f * __builtin_amdgcn_rcpf(e + 1.0f);
}

__device__ __forceinline__ float dot2acc(h2 a, h2 b, float c) {
#if __has_builtin(__builtin_amdgcn_fdot2)
    return __builtin_amdgcn_fdot2(a, b, c, false);
#else
    c = fmaf((float)a[0], (float)b[0], c);
    return fmaf((float)a[1], (float)b[1], c);
#endif
}

// ---- prep: 48 blocks; block b: 96 packed wq h2 + d-slice [2b,2b+2) of kvw ----
__global__ __launch_bounds__(256) void gst_prep(
    const float* __restrict__ tokens,
    const float* __restrict__ Wq,
    const float* __restrict__ Wk,
    const float* __restrict__ Wv,
    char* __restrict__ ws)
{
    h2* wq2 = (h2*)(ws + WS_WQ2);
    float* kvw = (float*)(ws + WS_KVW);
    h2* wvp = (h2*)(ws + WS_WVP);
    const int b = blockIdx.x;
    const int tid = threadIdx.x;

    // packed swizzled Wq: 4608 h2 total = 48 blocks x 96
    if (tid < 96) {
        int o = b * 96 + tid;
        int m = o % 6;
        int r = o / 6;
        int l = r & 7;
        int i = (r >> 3) & 7;
        int cc = r >> 6;
        int row = 8 * cc + (l ^ i);
        int c0 = l * XPL + 2 * m;
        wq2[o] = pack_h2(Wq[row * TD + c0], Wq[row * TD + c0 + 1]);
    }
    // kvw[d][4+n] = tanh(tanh(tokens[n] . Wk[d]))  (pre-tanh'd, addition formula)
    if (tid < 2 * NT) {
        int d = 2 * b + tid / NT;
        int n = tid % NT;
        const float4* tr = (const float4*)(tokens + n * TD);
        const float4* wr = (const float4*)(Wk + d * TD);
        float acc = 0.0f;
        #pragma unroll
        for (int j = 0; j < TD / 4; ++j) {
            float4 a = tr[j];
            float4 w = wr[j];
            acc = fmaf(a.x, w.x, acc);
            acc = fmaf(a.y, w.y, acc);
            acc = fmaf(a.z, w.z, acc);
            acc = fmaf(a.w, w.w, acc);
        }
        kvw[d * 16 + 4 + n] = fast_tanh(fast_tanh(acc));
    }
    if (tid < 2 * NH) { // wv (kept for layout compat) + pad
        int d = 2 * b + (tid >> 2);
        int h = tid & 3;
        kvw[d * 16 + h] = Wv[h * TD + d];
    }
    if (tid < 2 * 2) {
        int d = 2 * b + (tid >> 1);
        kvw[d * 16 + 14 + (tid & 1)] = 0.0f;
    }
    // wvp pairs (block 0): 192 items
    if (b == 0 && tid < 192) {
        int pp = tid >> 5;
        int l = (tid >> 2) & 7;
        int h = tid & 3;
        wvp[(pp * 8 + l) * 4 + h] =
            pack_h2(Wv[h * TD + 16 * pp + l], Wv[h * TD + 16 * pp + 8 + l]);
    }
}

// ---- main: LDS 18432 B -> 8 blocks/CU, grid 2048 = one tail-free round ----
__global__ __launch_bounds__(TPB, 6) void gst_main(
    const float* __restrict__ ref_emb,
    const float* __restrict__ tokens,
    const char* __restrict__ ws,
    float* __restrict__ out)
{
    __shared__ __align__(16) h2 wq2S[12 * 8 * 8 * 6]; // 18432 B

    const int tid = threadIdx.x;
    const int pos = (blockIdx.x * TPB + tid) >> 3;
    const int l = tid & 7;
    const float* kvw = (const float*)(ws + WS_KVW);
    const h2* wvp = (const h2*)(ws + WS_WVP);

    // prefetch this lane's x twelfth (3 float4), overlapping the LDS copy
    const float4* xr = (const float4*)(ref_emb + (size_t)pos * TD + l * XPL);
    float4 x0 = xr[0], x1 = xr[1], x2 = xr[2];

    // stage packed wq -> LDS: 1152 float4 over 256 threads
    {
        const float4* src = (const float4*)ws;
        float4* dst = (float4*)wq2S;
        #pragma unroll
        for (int i = 0; i < 4; ++i)
            dst[tid + i * TPB] = src[tid + i * TPB];
        if (tid < 128) dst[tid + 4 * TPB] = src[tid + 4 * TPB];
    }

    h2 xh[6];
    xh[0] = pack_h2(x0.x, x0.y); xh[1] = pack_h2(x0.z, x0.w);
    xh[2] = pack_h2(x1.x, x1.y); xh[3] = pack_h2(x1.z, x1.w);
    xh[4] = pack_h2(x2.x, x2.y); xh[5] = pack_h2(x2.z, x2.w);
    __syncthreads();

    union U2 { float2 f; h2 h[2]; };

    // ---- q phase: 12 groups of 8 rows; lane's q[cc] = tanh(tanh(raw(8cc+l))) --
    float q[12];
    #pragma unroll 2
    for (int cc = 0; cc < 12; ++cc) {
        float p[8];
        #pragma unroll
        for (int i = 0; i < 8; ++i) {
            const h2* wp = wq2S + (((cc * 8 + i) * 8) + l) * 6;
            U2 a, b, c;
            a.f = *(const float2*)(wp);     // h2 0,1
            b.f = *(const float2*)(wp + 2); // h2 2,3
            c.f = *(const float2*)(wp + 4); // h2 4,5
            float acc = 0.0f;
            acc = dot2acc(xh[0], a.h[0], acc);
            acc = dot2acc(xh[1], a.h[1], acc);
            acc = dot2acc(xh[2], b.h[0], acc);
            acc = dot2acc(xh[3], b.h[1], acc);
            acc = dot2acc(xh[4], c.h[0], acc);
            acc = dot2acc(xh[5], c.h[1], acc);
            p[i] = acc;
        }
        // select-free xor butterfly: p[i] holds row l^i -> partner has it at i^m
        p[0] += __shfl_xor(p[1], 1);
        p[2] += __shfl_xor(p[3], 1);
        p[4] += __shfl_xor(p[5], 1);
        p[6] += __shfl_xor(p[7], 1);
        p[0] += __shfl_xor(p[2], 2);
        p[4] += __shfl_xor(p[6], 2);
        p[0] += __shfl_xor(p[4], 4);
        q[cc] = fast_tanh(fast_tanh(p[0]));
    }

    float logits[NT][NH];
    #pragma unroll
    for (int n = 0; n < NT; ++n)
        #pragma unroll
        for (int h = 0; h < NH; ++h) logits[n][h] = 0.0f;

    // ---- s-phase over 6 d-pairs: d1 = 16pp+l (q[2pp]), d2 = d1+8 (q[2pp+1]) --
    #pragma unroll
    for (int pp = 0; pp < 6; ++pp) {
        const int d1 = 16 * pp + l;
        const float t1 = q[2 * pp], t2 = q[2 * pp + 1];

        const float* r1 = kvw + d1 * 16;
        const float* r2 = kvw + (d1 + 8) * 16;
        const float4 ka1 = *(const float4*)(r1 + 4);
        const float4 kb1 = *(const float4*)(r1 + 8);
        const float2 kc1 = *(const float2*)(r1 + 12);
        const float4 ka2 = *(const float4*)(r2 + 4);
        const float4 kb2 = *(const float4*)(r2 + 8);
        const float2 kc2 = *(const float2*)(r2 + 12);
        const float kv1[NT] = {ka1.x, ka1.y, ka1.z, ka1.w, kb1.x, kb1.y, kb1.z, kb1.w, kc1.x, kc1.y};
        const float kv2[NT] = {ka2.x, ka2.y, ka2.z, ka2.w, kb2.x, kb2.y, kb2.z, kb2.w, kc2.x, kc2.y};

        const h2* wrow = &wvp[(pp * 8 + l) * 4];
        const h2 w0 = wrow[0], w1 = wrow[1], w2 = wrow[2], w3 = wrow[3];

        #pragma unroll
        for (int n = 0; n < NT; ++n) {
            // s = tanh(q + k) via addition formula on pre-tanh'd values
            float s1 = (t1 + kv1[n]) * __builtin_amdgcn_rcpf(fmaf(t1, kv1[n], 1.0f));
            float s2 = (t2 + kv2[n]) * __builtin_amdgcn_rcpf(fmaf(t2, kv2[n], 1.0f));
            h2 sp = pack_h2(s1, s2);
            logits[n][0] = dot2acc(sp, w0, logits[n][0]);
            logits[n][1] = dot2acc(sp, w1, logits[n][1]);
            logits[n][2] = dot2acc(sp, w2, logits[n][2]);
            logits[n][3] = dot2acc(sp, w3, logits[n][3]);
        }
    }

    // ---- logits reduce-scatter: lane ends with lh[n] for head h = l&3 ----
    const bool myb0 = (l & 1) != 0;
    const bool myb1 = (l & 2) != 0;
    float lh[NT];
    #pragma unroll
    for (int n = 0; n < NT; ++n) {
        float L0 = logits[n][0], L1 = logits[n][1];
        float L2 = logits[n][2], L3 = logits[n][3];
        L0 += __shfl_xor(L0, 4);
        L1 += __shfl_xor(L1, 4);
        L2 += __shfl_xor(L2, 4);
        L3 += __shfl_xor(L3, 4);
        float m0 = myb1 ? L2 : L0, m1 = myb1 ? L3 : L1;
        float t0 = myb1 ? L0 : L2, t1 = myb1 ? L1 : L3;
        m0 += __shfl_xor(t0, 2);
        m1 += __shfl_xor(t1, 2);
        float mm = myb0 ? m1 : m0, tt = myb0 ? m0 : m1;
        lh[n] = mm + __shfl_xor(tt, 1);
    }

    // ---- per-lane softmax (head l&3); wn[n] = mean_h attn ----
    float m = lh[0];
    #pragma unroll
    for (int n = 1; n < NT; ++n) m = fmaxf(m, lh[n]);
    float e[NT];
    float ssum = 0.0f;
    #pragma unroll
    for (int n = 0; n < NT; ++n) {
        e[n] = __expf(lh[n] - m);
        ssum += e[n];
    }
    const float inv = 0.25f * __builtin_amdgcn_rcpf(ssum);
    float wn[NT];
    #pragma unroll
    for (int n = 0; n < NT; ++n) {
        float v = e[n] * inv;
        v += __shfl_xor(v, 1);
        v += __shfl_xor(v, 2);
        wn[n] = v;
    }

    // ---- style + store, coalesced: lane handles float4-index l + 8*jj ----
    float4* ob = (float4*)(out + (size_t)pos * TD);
    const float4* t4 = (const float4*)tokens;
    #pragma unroll
    for (int jj = 0; jj < 3; ++jj) {
        const int d4 = l + 8 * jj;
        float4 o = make_float4(0.f, 0.f, 0.f, 0.f);
        #pragma unroll
        for (int n = 0; n < NT; ++n) {
            float4 t = t4[n * (TD / 4) + d4];
            o.x = fmaf(wn[n], t.x, o.x);
            o.y = fmaf(wn[n], t.y, o.y);
            o.z = fmaf(wn[n], t.z, o.z);
            o.w = fmaf(wn[n], t.w, o.w);
        }
        ob[d4] = o;
    }
}

extern "C" void kernel_launch(void* const* d_in, const int* in_sizes, int n_in,
                              void* d_out, int out_size, void* d_ws, size_t ws_size,
                              hipStream_t stream) {
    const float* ref_emb = (const float*)d_in[0];
    const float* tokens  = (const float*)d_in[1];
    const float* Wq      = (const float*)d_in[2];
    const float* Wk      = (const float*)d_in[3];
    const float* Wv      = (const float*)d_in[4];
    float* out = (float*)d_out;

    gst_prep<<<48, 256, 0, stream>>>(tokens, Wq, Wk, Wv, (char*)d_ws);
    gst_main<<<(NPOS * LPP) / TPB, TPB, 0, stream>>>(ref_emb, tokens,
                                                     (const char*)d_ws, out);
}

// Round 16
// 62.882 us; speedup vs baseline: 1.7321x; 1.7321x over previous
//
#include <hip/hip_runtime.h>
#include <cstddef>

#define NT 10            // NUM_TOKENS
#define TD 96            // TOKEN_DIM == REF_DIM
#define NH 4             // NUM_HEADS
#define NPOS (32 * 2048) // B*T positions
#define TPB 256
#define LPP 8            // lanes per position
#define XPL 12           // x elems per lane (TD / LPP)

// workspace layout (bytes)
// wq2 packed swizzled Wq f16: [cc=12][i=8][l=8][6 h2] = 18432 B.
//   element (cc,i,l,m) = pack(Wq[8cc+(l^i)][l*12+2m], Wq[8cc+(l^i)][l*12+2m+1])
#define WS_WQ2 0
#define WS_KVW 18432     // float kvw[96][16]: row d = [wv0..3 | kv0..9 | pad2] (6144 B)
#define WS_WVP 24576     // h2 wvp[6][8][4]: (Wv[h][16pp+l], Wv[h][16pp+8+l]) (768 B)
#define WS_BYTES 25344

typedef _Float16 h2 __attribute__((ext_vector_type(2)));

__device__ __forceinline__ h2 pack_h2(float a, float b) {
    return __builtin_bit_cast(h2, __builtin_amdgcn_cvt_pkrtz(a, b));
}

__device__ __forceinline__ float fast_tanh(float x) {
    // tanh(x) = 1 - 2/(exp(2x)+1); exact limits at +/-inf, ~1e-6 rel error
    float e = __expf(2.0f * x);
    return 1.0f - 2.0f * __builtin_amdgcn_rcpf(e + 1.0f);
}

__device__ __forceinline__ float dot2acc(h2 a, h2 b, float c) {
#if __has_builtin(__builtin_amdgcn_fdot2)
    return __builtin_amdgcn_fdot2(a, b, c, false);
#else
    c = fmaf((float)a[0], (float)b[0], c);
    return fmaf((float)a[1], (float)b[1], c);
#endif
}

// ---- prep: 48 blocks; block b: 96 packed wq h2 + d-slice [2b,2b+2) of kvw ----
__global__ __launch_bounds__(256) void gst_prep(
    const float* __restrict__ tokens,
    const float* __restrict__ Wq,
    const float* __restrict__ Wk,
    const float* __restrict__ Wv,
    char* __restrict__ ws)
{
    h2* wq2 = (h2*)(ws + WS_WQ2);
    float* kvw = (float*)(ws + WS_KVW);
    h2* wvp = (h2*)(ws + WS_WVP);
    const int b = blockIdx.x;
    const int tid = threadIdx.x;

    // packed swizzled Wq: 4608 h2 total = 48 blocks x 96
    if (tid < 96) {
        int o = b * 96 + tid;
        int m = o % 6;
        int r = o / 6;
        int l = r & 7;
        int i = (r >> 3) & 7;
        int cc = r >> 6;
        int row = 8 * cc + (l ^ i);
        int c0 = l * XPL + 2 * m;
        wq2[o] = pack_h2(Wq[row * TD + c0], Wq[row * TD + c0 + 1]);
    }
    // kvw[d][4+n] = tanh(tanh(tokens[n] . Wk[d]))  (pre-tanh'd, addition formula)
    if (tid < 2 * NT) {
        int d = 2 * b + tid / NT;
        int n = tid % NT;
        const float4* tr = (const float4*)(tokens + n * TD);
        const float4* wr = (const float4*)(Wk + d * TD);
        float acc = 0.0f;
        #pragma unroll
        for (int j = 0; j < TD / 4; ++j) {
            float4 a = tr[j];
            float4 w = wr[j];
            acc = fmaf(a.x, w.x, acc);
            acc = fmaf(a.y, w.y, acc);
            acc = fmaf(a.z, w.z, acc);
            acc = fmaf(a.w, w.w, acc);
        }
        kvw[d * 16 + 4 + n] = fast_tanh(fast_tanh(acc));
    }
    if (tid < 2 * NH) {
        int d = 2 * b + (tid >> 2);
        int h = tid & 3;
        kvw[d * 16 + h] = Wv[h * TD + d];
    }
    if (tid < 2 * 2) {
        int d = 2 * b + (tid >> 1);
        kvw[d * 16 + 14 + (tid & 1)] = 0.0f;
    }
    // wvp pairs (block 0): 192 items
    if (b == 0 && tid < 192) {
        int pp = tid >> 5;
        int l = (tid >> 2) & 7;
        int h = tid & 3;
        wvp[(pp * 8 + l) * 4 + h] =
            pack_h2(Wv[h * TD + 16 * pp + l], Wv[h * TD + 16 * pp + 8 + l]);
    }
}

// per-lane q for row-group cc: partial dots over 8 swizzled rows + butterfly.
// Returns tanh(tanh(raw q of row 8cc+l)). All indices compile-time constants.
#define QCALC(CC, DST)                                                        \
    {                                                                         \
        float p0, p1, p2, p3, p4, p5, p6, p7;                                 \
        _Pragma("unroll")                                                     \
        for (int only = 0; only < 1; ++only) {                                \
            const h2* base = wq2S + (CC) * 384 + l * 6;                       \
            union U2 { float2 f; h2 h[2]; };                                  \
            U2 a, b, c;                                                       \
            float* pv[8] = {&p0, &p1, &p2, &p3, &p4, &p5, &p6, &p7};          \
            _Pragma("unroll")                                                 \
            for (int i = 0; i < 8; ++i) {                                     \
                const h2* wp = base + i * 48;                                 \
                a.f = *(const float2*)(wp);                                   \
                b.f = *(const float2*)(wp + 2);                               \
                c.f = *(const float2*)(wp + 4);                               \
                float acc = 0.0f;                                             \
                acc = dot2acc(xh0, a.h[0], acc);                              \
                acc = dot2acc(xh1, a.h[1], acc);                              \
                acc = dot2acc(xh2, b.h[0], acc);                              \
                acc = dot2acc(xh3, b.h[1], acc);                              \
                acc = dot2acc(xh4, c.h[0], acc);                              \
                acc = dot2acc(xh5, c.h[1], acc);                              \
                *pv[i] = acc;                                                 \
            }                                                                 \
        }                                                                     \
        p0 += __shfl_xor(p1, 1);                                              \
        p2 += __shfl_xor(p3, 1);                                              \
        p4 += __shfl_xor(p5, 1);                                              \
        p6 += __shfl_xor(p7, 1);                                              \
        p0 += __shfl_xor(p2, 2);                                              \
        p4 += __shfl_xor(p6, 2);                                              \
        p0 += __shfl_xor(p4, 4);                                              \
        DST = fast_tanh(fast_tanh(p0));                                       \
    }

// ---- main: LDS 18432 B -> 8 blocks/CU, grid 2048 = one tail-free round ----
__global__ __launch_bounds__(TPB, 6) void gst_main(
    const float* __restrict__ ref_emb,
    const float* __restrict__ tokens,
    const char* __restrict__ ws,
    float* __restrict__ out)
{
    __shared__ __align__(16) h2 wq2S[12 * 8 * 8 * 6]; // 18432 B

    const int tid = threadIdx.x;
    const int pos = (blockIdx.x * TPB + tid) >> 3;
    const int l = tid & 7;
    const float* kvw = (const float*)(ws + WS_KVW);
    const h2* wvp = (const h2*)(ws + WS_WVP);

    // prefetch this lane's x twelfth (3 float4), overlapping the LDS copy
    const float4* xr = (const float4*)(ref_emb + (size_t)pos * TD + l * XPL);
    float4 x0 = xr[0], x1 = xr[1], x2 = xr[2];

    // stage packed wq -> LDS: 1152 float4 over 256 threads
    {
        const float4* src = (const float4*)ws;
        float4* dst = (float4*)wq2S;
        #pragma unroll
        for (int i = 0; i < 4; ++i)
            dst[tid + i * TPB] = src[tid + i * TPB];
        if (tid < 128) dst[tid + 4 * TPB] = src[tid + 4 * TPB];
    }

    const h2 xh0 = pack_h2(x0.x, x0.y), xh1 = pack_h2(x0.z, x0.w);
    const h2 xh2 = pack_h2(x1.x, x1.y), xh3 = pack_h2(x1.z, x1.w);
    const h2 xh4 = pack_h2(x2.x, x2.y), xh5 = pack_h2(x2.z, x2.w);
    __syncthreads();

    float logits[NT][NH];
    #pragma unroll
    for (int n = 0; n < NT; ++n)
        #pragma unroll
        for (int h = 0; h < NH; ++h) logits[n][h] = 0.0f;

    // ---- fused q + s phase per d-pair pp: t1 (d=16pp+l), t2 (d=16pp+8+l) ----
    #pragma unroll
    for (int pp = 0; pp < 6; ++pp) {
        float t1, t2;
        QCALC(2 * pp, t1)
        QCALC(2 * pp + 1, t2)

        const int d1 = 16 * pp + l;
        const float* r1 = kvw + d1 * 16;
        const float* r2 = kvw + (d1 + 8) * 16;
        const float4 ka1 = *(const float4*)(r1 + 4);
        const float4 kb1 = *(const float4*)(r1 + 8);
        const float2 kc1 = *(const float2*)(r1 + 12);
        const float4 ka2 = *(const float4*)(r2 + 4);
        const float4 kb2 = *(const float4*)(r2 + 8);
        const float2 kc2 = *(const float2*)(r2 + 12);
        const float kv1[NT] = {ka1.x, ka1.y, ka1.z, ka1.w, kb1.x, kb1.y, kb1.z, kb1.w, kc1.x, kc1.y};
        const float kv2[NT] = {ka2.x, ka2.y, ka2.z, ka2.w, kb2.x, kb2.y, kb2.z, kb2.w, kc2.x, kc2.y};

        const h2* wrow = &wvp[(pp * 8 + l) * 4];
        const h2 w0 = wrow[0], w1 = wrow[1], w2 = wrow[2], w3 = wrow[3];

        #pragma unroll
        for (int n = 0; n < NT; ++n) {
            // s = tanh(q + k) via addition formula on pre-tanh'd values
            float s1 = (t1 + kv1[n]) * __builtin_amdgcn_rcpf(fmaf(t1, kv1[n], 1.0f));
            float s2 = (t2 + kv2[n]) * __builtin_amdgcn_rcpf(fmaf(t2, kv2[n], 1.0f));
            h2 sp = pack_h2(s1, s2);
            logits[n][0] = dot2acc(sp, w0, logits[n][0]);
            logits[n][1] = dot2acc(sp, w1, logits[n][1]);
            logits[n][2] = dot2acc(sp, w2, logits[n][2]);
            logits[n][3] = dot2acc(sp, w3, logits[n][3]);
        }
    }

    // ---- logits reduce-scatter: lane ends with lh[n] for head h = l&3 ----
    const bool myb0 = (l & 1) != 0;
    const bool myb1 = (l & 2) != 0;
    float lh[NT];
    #pragma unroll
    for (int n = 0; n < NT; ++n) {
        float L0 = logits[n][0], L1 = logits[n][1];
        float L2 = logits[n][2], L3 = logits[n][3];
        L0 += __shfl_xor(L0, 4);
        L1 += __shfl_xor(L1, 4);
        L2 += __shfl_xor(L2, 4);
        L3 += __shfl_xor(L3, 4);
        float m0 = myb1 ? L2 : L0, m1 = myb1 ? L3 : L1;
        float t0 = myb1 ? L0 : L2, t1 = myb1 ? L1 : L3;
        m0 += __shfl_xor(t0, 2);
        m1 += __shfl_xor(t1, 2);
        float mm = myb0 ? m1 : m0, tt = myb0 ? m0 : m1;
        lh[n] = mm + __shfl_xor(tt, 1);
    }

    // ---- per-lane softmax (head l&3); wn[n] = mean_h attn ----
    float m = lh[0];
    #pragma unroll
    for (int n = 1; n < NT; ++n) m = fmaxf(m, lh[n]);
    float e[NT];
    float ssum = 0.0f;
    #pragma unroll
    for (int n = 0; n < NT; ++n) {
        e[n] = __expf(lh[n] - m);
        ssum += e[n];
    }
    const float inv = 0.25f * __builtin_amdgcn_rcpf(ssum);
    float wn[NT];
    #pragma unroll
    for (int n = 0; n < NT; ++n) {
        float v = e[n] * inv;
        v += __shfl_xor(v, 1);
        v += __shfl_xor(v, 2);
        wn[n] = v;
    }

    // ---- style + store, coalesced: lane handles float4-index l + 8*jj ----
    float4* ob = (float4*)(out + (size_t)pos * TD);
    const float4* t4 = (const float4*)tokens;
    #pragma unroll
    for (int jj = 0; jj < 3; ++jj) {
        const int d4 = l + 8 * jj;
        float4 o = make_float4(0.f, 0.f, 0.f, 0.f);
        #pragma unroll
        for (int n = 0; n < NT; ++n) {
            float4 t = t4[n * (TD / 4) + d4];
            o.x = fmaf(wn[n], t.x, o.x);
            o.y = fmaf(wn[n], t.y, o.y);
            o.z = fmaf(wn[n], t.z, o.z);
            o.w = fmaf(wn[n], t.w, o.w);
        }
        ob[d4] = o;
    }
}

extern "C" void kernel_launch(void* const* d_in, const int* in_sizes, int n_in,
                              void* d_out, int out_size, void* d_ws, size_t ws_size,
                              hipStream_t stream) {
    const float* ref_emb = (const float*)d_in[0];
    const float* tokens  = (const float*)d_in[1];
    const float* Wq      = (const float*)d_in[2];
    const float* Wk      = (const float*)d_in[3];
    const float* Wv      = (const float*)d_in[4];
    float* out = (float*)d_out;

    gst_prep<<<48, 256, 0, stream>>>(tokens, Wq, Wk, Wv, (char*)d_ws);
    gst_main<<<(NPOS * LPP) / TPB, TPB, 0, stream>>>(ref_emb, tokens,
                                                     (const char*)d_ws, out);
}

// Round 17
// 52.809 us; speedup vs baseline: 2.0625x; 1.1908x over previous
//
#include <hip/hip_runtime.h>
#include <rocwmma/rocwmma.hpp>
#include <cstddef>

#define NT 10            // NUM_TOKENS
#define TD 96            // TOKEN_DIM == REF_DIM
#define NH 4             // NUM_HEADS
#define NPOS (32 * 2048) // B*T positions
#define TPB 256
#define PPB 32           // positions per block; 8 lanes/pos in s-phase
#define LDX 104          // padded leading dim for xS (f16) and tqS (f32)

// workspace layout (bytes)
#define WS_WQ 0          // f16 wq16[96][96] row-major (18432 B) -> wmma B (col_major view)
#define WS_KVW 18432     // float kvw[96][16]: row d = [wv0..3 | kv0..9 | pad2] (6144 B)
#define WS_WVP 24576     // h2 wvp[6][8][4]: (Wv[h][16pp+l], Wv[h][16pp+8+l]) (768 B)
#define WS_BYTES 25344

typedef _Float16 h2 __attribute__((ext_vector_type(2)));

__device__ __forceinline__ h2 pack_h2(float a, float b) {
    return __builtin_bit_cast(h2, __builtin_amdgcn_cvt_pkrtz(a, b));
}

__device__ __forceinline__ float fast_tanh(float x) {
    // tanh(x) = 1 - 2/(exp(2x)+1); exact limits at +/-inf, ~1e-6 rel error
    float e = __expf(2.0f * x);
    return 1.0f - 2.0f * __builtin_amdgcn_rcpf(e + 1.0f);
}

__device__ __forceinline__ float dot2acc(h2 a, h2 b, float c) {
#if __has_builtin(__builtin_amdgcn_fdot2)
    return __builtin_amdgcn_fdot2(a, b, c, false);
#else
    c = fmaf((float)a[0], (float)b[0], c);
    return fmaf((float)a[1], (float)b[1], c);
#endif
}

// ---- prep: 48 blocks; block b owns d-slice [2b, 2b+2); block 0 also wvp ----
__global__ __launch_bounds__(256) void gst_prep(
    const float* __restrict__ tokens,
    const float* __restrict__ Wq,
    const float* __restrict__ Wk,
    const float* __restrict__ Wv,
    char* __restrict__ ws)
{
    h2* wqH = (h2*)(ws + WS_WQ);
    float* kvw = (float*)(ws + WS_KVW);
    h2* wvp = (h2*)(ws + WS_WVP);
    const int b = blockIdx.x;
    const int tid = threadIdx.x;

    // Wq rows -> f16 (2 rows x 48 pairs); [96][48] h2 == [96][96] f16 row-major
    if (tid < 2 * (TD / 2)) {
        int r = 2 * b + tid / (TD / 2);
        int c = tid % (TD / 2);
        float2 f = ((const float2*)(Wq + r * TD))[c];
        wqH[r * (TD / 2) + c] = pack_h2(f.x, f.y);
    }
    // kvw[d][4+n] = tanh(tanh(tokens[n] . Wk[d]))  (pre-tanh'd, addition formula)
    if (tid < 2 * NT) {
        int d = 2 * b + tid / NT;
        int n = tid % NT;
        const float4* tr = (const float4*)(tokens + n * TD);
        const float4* wr = (const float4*)(Wk + d * TD);
        float acc = 0.0f;
        #pragma unroll
        for (int j = 0; j < TD / 4; ++j) {
            float4 a = tr[j];
            float4 w = wr[j];
            acc = fmaf(a.x, w.x, acc);
            acc = fmaf(a.y, w.y, acc);
            acc = fmaf(a.z, w.z, acc);
            acc = fmaf(a.w, w.w, acc);
        }
        kvw[d * 16 + 4 + n] = fast_tanh(fast_tanh(acc));
    }
    if (tid < 2 * NH) {
        int d = 2 * b + (tid >> 2);
        int h = tid & 3;
        kvw[d * 16 + h] = Wv[h * TD + d];
    }
    if (tid < 2 * 2) {
        int d = 2 * b + (tid >> 1);
        kvw[d * 16 + 14 + (tid & 1)] = 0.0f;
    }
    // wvp pairs (block 0): 192 items
    if (b == 0 && tid < 192) {
        int pp = tid >> 5;
        int l = (tid >> 2) & 7;
        int h = tid & 3;
        wvp[(pp * 8 + l) * 4 + h] =
            pack_h2(Wv[h * TD + 16 * pp + l], Wv[h * TD + 16 * pp + 8 + l]);
    }
}

// ---- main: rocWMMA q-projection -> tqS (f32, LDS) -> proven s-phase ----
__global__ __launch_bounds__(TPB, 6) void gst_main(
    const float* __restrict__ ref_emb,
    const float* __restrict__ tokens,
    const char* __restrict__ ws,
    float* __restrict__ out)
{
    __shared__ __align__(16) _Float16 xS[PPB * LDX]; //  6656 B, x tile as f16
    __shared__ __align__(16) float tqS[PPB * LDX];   // 13312 B, tanh(tanh(q)) f32

    const int tid = threadIdx.x;
    const int P0 = blockIdx.x * PPB;

    // ---- stage x -> LDS f16 (padded ld=104); 768 float4 coalesced ----
    {
        const float4* src = (const float4*)(ref_emb + (size_t)P0 * TD);
        #pragma unroll
        for (int it = 0; it < 3; ++it) {
            int t = tid + it * TPB;
            int row = t / (TD / 4);
            int c4 = t - row * (TD / 4);
            float4 v = src[t];
            h2* dst = (h2*)(xS + row * LDX + c4 * 4);
            dst[0] = pack_h2(v.x, v.y);
            dst[1] = pack_h2(v.z, v.w);
        }
    }
    __syncthreads();

    // ---- MFMA q phase via rocWMMA: wave w -> pos-half (w>>1), d-half (w&1) --
    {
        using namespace rocwmma;
        const int wid = tid >> 6;
        const int ph = wid >> 1;
        const int dh = wid & 1;

        fragment<matrix_a, 16, 16, 16, float16_t, row_major> fa[6];
        #pragma unroll
        for (int kb = 0; kb < 6; ++kb)
            load_matrix_sync(fa[kb],
                (const float16_t*)(xS + ph * 16 * LDX + kb * 16), LDX);

        const float16_t* wq16 = (const float16_t*)(ws + WS_WQ);
        #pragma unroll
        for (int t = 0; t < 3; ++t) {
            fragment<accumulator, 16, 16, 16, float> fc;
            fill_fragment(fc, 0.0f);
            #pragma unroll
            for (int kb = 0; kb < 6; ++kb) {
                fragment<matrix_b, 16, 16, 16, float16_t, col_major> fb;
                // B(k, d) = Wq[d][k]: row-major Wq == col_major (k,d), ld = TD
                load_matrix_sync(fb, wq16 + (dh * 3 + t) * 16 * TD + kb * 16, TD);
                mma_sync(fc, fa[kb], fb, fc);
            }
            #pragma unroll
            for (int e = 0; e < fc.num_elements; ++e)
                fc.x[e] = fast_tanh(fast_tanh(fc.x[e]));
            store_matrix_sync(tqS + ph * 16 * LDX + (dh * 3 + t) * 16, fc, LDX,
                              mem_row_major);
        }
    }
    __syncthreads();

    // ---- s-phase: 8 lanes/pos, lane owns d-pair {16pp+l, 16pp+8+l} ----
    const int prow = tid >> 3;
    const int pos = P0 + prow;
    const int l = tid & 7;
    const float* kvw = (const float*)(ws + WS_KVW);
    const h2* wvp = (const h2*)(ws + WS_WVP);
    const float* tqrow = tqS + prow * LDX;

    float logits[NT][NH];
    #pragma unroll
    for (int n = 0; n < NT; ++n)
        #pragma unroll
        for (int h = 0; h < NH; ++h) logits[n][h] = 0.0f;

    #pragma unroll
    for (int pp = 0; pp < 6; ++pp) {
        const int d1 = 16 * pp + l;
        const float t1 = tqrow[d1];
        const float t2 = tqrow[d1 + 8];

        const float* r1 = kvw + d1 * 16;
        const float* r2 = kvw + (d1 + 8) * 16;
        const float4 ka1 = *(const float4*)(r1 + 4);
        const float4 kb1 = *(const float4*)(r1 + 8);
        const float2 kc1 = *(const float2*)(r1 + 12);
        const float4 ka2 = *(const float4*)(r2 + 4);
        const float4 kb2 = *(const float4*)(r2 + 8);
        const float2 kc2 = *(const float2*)(r2 + 12);
        const float kv1[NT] = {ka1.x, ka1.y, ka1.z, ka1.w, kb1.x, kb1.y, kb1.z, kb1.w, kc1.x, kc1.y};
        const float kv2[NT] = {ka2.x, ka2.y, ka2.z, ka2.w, kb2.x, kb2.y, kb2.z, kb2.w, kc2.x, kc2.y};

        const h2* wrow = &wvp[(pp * 8 + l) * 4];
        const h2 w0 = wrow[0], w1 = wrow[1], w2 = wrow[2], w3 = wrow[3];

        #pragma unroll
        for (int n = 0; n < NT; ++n) {
            // s = tanh(q + k) via addition formula on pre-tanh'd values
            float s1 = (t1 + kv1[n]) * __builtin_amdgcn_rcpf(fmaf(t1, kv1[n], 1.0f));
            float s2 = (t2 + kv2[n]) * __builtin_amdgcn_rcpf(fmaf(t2, kv2[n], 1.0f));
            h2 sp = pack_h2(s1, s2);
            logits[n][0] = dot2acc(sp, w0, logits[n][0]);
            logits[n][1] = dot2acc(sp, w1, logits[n][1]);
            logits[n][2] = dot2acc(sp, w2, logits[n][2]);
            logits[n][3] = dot2acc(sp, w3, logits[n][3]);
        }
    }

    // ---- logits reduce-scatter: lane ends with lh[n] for head h = l&3 ----
    const bool myb0 = (l & 1) != 0;
    const bool myb1 = (l & 2) != 0;
    float lh[NT];
    #pragma unroll
    for (int n = 0; n < NT; ++n) {
        float L0 = logits[n][0], L1 = logits[n][1];
        float L2 = logits[n][2], L3 = logits[n][3];
        L0 += __shfl_xor(L0, 4);
        L1 += __shfl_xor(L1, 4);
        L2 += __shfl_xor(L2, 4);
        L3 += __shfl_xor(L3, 4);
        float m0 = myb1 ? L2 : L0, m1 = myb1 ? L3 : L1;
        float t0 = myb1 ? L0 : L2, t1 = myb1 ? L1 : L3;
        m0 += __shfl_xor(t0, 2);
        m1 += __shfl_xor(t1, 2);
        float mm = myb0 ? m1 : m0, tt = myb0 ? m0 : m1;
        lh[n] = mm + __shfl_xor(tt, 1);
    }

    // ---- per-lane softmax (head l&3); wn[n] = mean_h attn ----
    float m = lh[0];
    #pragma unroll
    for (int n = 1; n < NT; ++n) m = fmaxf(m, lh[n]);
    float e[NT];
    float ssum = 0.0f;
    #pragma unroll
    for (int n = 0; n < NT; ++n) {
        e[n] = __expf(lh[n] - m);
        ssum += e[n];
    }
    const float inv = 0.25f * __builtin_amdgcn_rcpf(ssum);
    float wn[NT];
    #pragma unroll
    for (int n = 0; n < NT; ++n) {
        float v = e[n] * inv;
        v += __shfl_xor(v, 1);
        v += __shfl_xor(v, 2);
        wn[n] = v;
    }

    // ---- style + store, coalesced: lane handles float4-index l + 8*jj ----
    float4* ob = (float4*)(out + (size_t)pos * TD);
    const float4* t4 = (const float4*)tokens;
    #pragma unroll
    for (int jj = 0; jj < 3; ++jj) {
        const int d4 = l + 8 * jj;
        float4 o = make_float4(0.f, 0.f, 0.f, 0.f);
        #pragma unroll
        for (int n = 0; n < NT; ++n) {
            float4 t = t4[n * (TD / 4) + d4];
            o.x = fmaf(wn[n], t.x, o.x);
            o.y = fmaf(wn[n], t.y, o.y);
            o.z = fmaf(wn[n], t.z, o.z);
            o.w = fmaf(wn[n], t.w, o.w);
        }
        ob[d4] = o;
    }
}

extern "C" void kernel_launch(void* const* d_in, const int* in_sizes, int n_in,
                              void* d_out, int out_size, void* d_ws, size_t ws_size,
                              hipStream_t stream) {
    const float* ref_emb = (const float*)d_in[0];
    const float* tokens  = (const float*)d_in[1];
    const float* Wq      = (const float*)d_in[2];
    const float* Wk      = (const float*)d_in[3];
    const float* Wv      = (const float*)d_in[4];
    float* out = (float*)d_out;

    gst_prep<<<48, 256, 0, stream>>>(tokens, Wq, Wk, Wv, (char*)d_ws);
    gst_main<<<NPOS / PPB, TPB, 0, stream>>>(ref_emb, tokens,
                                             (const char*)d_ws, out);
}

// Round 18
// 40.110 us; speedup vs baseline: 2.7155x; 1.3166x over previous
//
#include <hip/hip_runtime.h>
#include <rocwmma/rocwmma.hpp>
#include <cstddef>

#define NT 10            // NUM_TOKENS
#define TD 96            // TOKEN_DIM == REF_DIM
#define NH 4             // NUM_HEADS
#define NPOS (32 * 2048) // B*T positions
#define TPB 256
#define PPB 32           // positions per block; 8 lanes/pos in s-phase
#define LDX 104          // padded leading dim for xS (f16) and tqS (f32)

// workspace layout (bytes)
#define WS_WQ 0          // f16 wq16[96][96] row-major (18432 B) -> wmma B (col_major view)
#define WS_KV2 18432     // float kv2[96][12]: kv[d][n]=tanh(tanh(tok.Wk)), pad 2 (4608 B)
#define WS_WVP 23040     // h2 wvp[6][8][4]: (Wv[h][16pp+l], Wv[h][16pp+8+l]) (768 B)
#define WS_BYTES 23808

typedef _Float16 h2 __attribute__((ext_vector_type(2)));

__device__ __forceinline__ h2 pack_h2(float a, float b) {
    return __builtin_bit_cast(h2, __builtin_amdgcn_cvt_pkrtz(a, b));
}

__device__ __forceinline__ float fast_tanh(float x) {
    // tanh(x) = 1 - 2/(exp(2x)+1); exact limits at +/-inf, ~1e-6 rel error
    float e = __expf(2.0f * x);
    return 1.0f - 2.0f * __builtin_amdgcn_rcpf(e + 1.0f);
}

__device__ __forceinline__ float dot2acc(h2 a, h2 b, float c) {
#if __has_builtin(__builtin_amdgcn_fdot2)
    return __builtin_amdgcn_fdot2(a, b, c, false);
#else
    c = fmaf((float)a[0], (float)b[0], c);
    return fmaf((float)a[1], (float)b[1], c);
#endif
}

// ---- prep: 48 blocks; block b owns d-slice [2b, 2b+2); block 0 also wvp ----
__global__ __launch_bounds__(256) void gst_prep(
    const float* __restrict__ tokens,
    const float* __restrict__ Wq,
    const float* __restrict__ Wk,
    const float* __restrict__ Wv,
    char* __restrict__ ws)
{
    h2* wqH = (h2*)(ws + WS_WQ);
    float* kv2 = (float*)(ws + WS_KV2);
    h2* wvp = (h2*)(ws + WS_WVP);
    const int b = blockIdx.x;
    const int tid = threadIdx.x;

    // Wq rows -> f16 (2 rows x 48 pairs); [96][48] h2 == [96][96] f16 row-major
    if (tid < 2 * (TD / 2)) {
        int r = 2 * b + tid / (TD / 2);
        int c = tid % (TD / 2);
        float2 f = ((const float2*)(Wq + r * TD))[c];
        wqH[r * (TD / 2) + c] = pack_h2(f.x, f.y);
    }
    // kv2[d][n] = tanh(tanh(tokens[n] . Wk[d]))  (pre-tanh'd, addition formula)
    if (tid < 2 * NT) {
        int d = 2 * b + tid / NT;
        int n = tid % NT;
        const float4* tr = (const float4*)(tokens + n * TD);
        const float4* wr = (const float4*)(Wk + d * TD);
        float acc = 0.0f;
        #pragma unroll
        for (int j = 0; j < TD / 4; ++j) {
            float4 a = tr[j];
            float4 w = wr[j];
            acc = fmaf(a.x, w.x, acc);
            acc = fmaf(a.y, w.y, acc);
            acc = fmaf(a.z, w.z, acc);
            acc = fmaf(a.w, w.w, acc);
        }
        kv2[d * 12 + n] = fast_tanh(fast_tanh(acc));
    }
    if (tid < 2 * 2) { // zero the pad
        int d = 2 * b + (tid >> 1);
        kv2[d * 12 + 10 + (tid & 1)] = 0.0f;
    }
    // wvp pairs (block 0): 192 items
    if (b == 0 && tid < 192) {
        int pp = tid >> 5;
        int l = (tid >> 2) & 7;
        int h = tid & 3;
        wvp[(pp * 8 + l) * 4 + h] =
            pack_h2(Wv[h * TD + 16 * pp + l], Wv[h * TD + 16 * pp + 8 + l]);
    }
}

// ---- main: rocWMMA q-projection; xS LDS region reused for kv/wvp so the
//      s-phase runs entirely out of LDS while keeping 8 blocks/CU ----
__global__ __launch_bounds__(TPB, 6) void gst_main(
    const float* __restrict__ ref_emb,
    const float* __restrict__ tokens,
    const char* __restrict__ ws,
    float* __restrict__ out)
{
    __shared__ __align__(16) char buf[PPB * LDX * 2]; // 6656 B: xS f16, then kv/wvp
    __shared__ __align__(16) float tqS[PPB * LDX];    // 13312 B, tanh(tanh(q)) f32

    const int tid = threadIdx.x;
    const int P0 = blockIdx.x * PPB;
    _Float16* xS = (_Float16*)buf;

    // issue kv/wvp global->reg loads early (consumed after the wmma phase)
    const float4* srcKV = (const float4*)(ws + WS_KV2); // 336 float4 (kv+wvp)
    float4 rs0 = srcKV[tid];
    float4 rs1;
    if (tid < 80) rs1 = srcKV[256 + tid];

    // ---- stage x -> LDS f16 (padded ld=104); 768 float4 coalesced ----
    {
        const float4* src = (const float4*)(ref_emb + (size_t)P0 * TD);
        #pragma unroll
        for (int it = 0; it < 3; ++it) {
            int t = tid + it * TPB;
            int row = t / (TD / 4);
            int c4 = t - row * (TD / 4);
            float4 v = src[t];
            h2* dst = (h2*)(xS + row * LDX + c4 * 4);
            dst[0] = pack_h2(v.x, v.y);
            dst[1] = pack_h2(v.z, v.w);
        }
    }
    __syncthreads();

    // ---- MFMA q phase via rocWMMA: wave w -> pos-half (w>>1), d-half (w&1) --
    {
        using namespace rocwmma;
        const int wid = tid >> 6;
        const int ph = wid >> 1;
        const int dh = wid & 1;

        fragment<matrix_a, 16, 16, 16, float16_t, row_major> fa[6];
        #pragma unroll
        for (int kb = 0; kb < 6; ++kb)
            load_matrix_sync(fa[kb],
                (const float16_t*)(xS + ph * 16 * LDX + kb * 16), LDX);

        const float16_t* wq16 = (const float16_t*)(ws + WS_WQ);
        #pragma unroll
        for (int t = 0; t < 3; ++t) {
            fragment<accumulator, 16, 16, 16, float> fc;
            fill_fragment(fc, 0.0f);
            #pragma unroll
            for (int kb = 0; kb < 6; ++kb) {
                fragment<matrix_b, 16, 16, 16, float16_t, col_major> fb;
                // B(k, d) = Wq[d][k]: row-major Wq == col_major (k,d), ld = TD
                load_matrix_sync(fb, wq16 + (dh * 3 + t) * 16 * TD + kb * 16, TD);
                mma_sync(fc, fa[kb], fb, fc);
            }
            #pragma unroll
            for (int e = 0; e < fc.num_elements; ++e)
                fc.x[e] = fast_tanh(fast_tanh(fc.x[e]));
            store_matrix_sync(tqS + ph * 16 * LDX + (dh * 3 + t) * 16, fc, LDX,
                              mem_row_major);
        }
    }
    __syncthreads(); // xS reads done by all waves; tqS complete

    // ---- overwrite xS region with kv (4608 B) + wvp (768 B) ----
    {
        float4* dstKV = (float4*)buf;
        dstKV[tid] = rs0;
        if (tid < 80) dstKV[256 + tid] = rs1;
    }
    __syncthreads();

    const float* kvS = (const float*)buf;       // [96][12] f32, conflict-free
    const h2* wvpS = (const h2*)(buf + 4608);   // [6][8][4]

    // ---- s-phase: 8 lanes/pos, lane owns d-pair {16pp+l, 16pp+8+l} ----
    const int prow = tid >> 3;
    const int pos = P0 + prow;
    const int l = tid & 7;
    const float* tqrow = tqS + prow * LDX;

    float logits[NT][NH];
    #pragma unroll
    for (int n = 0; n < NT; ++n)
        #pragma unroll
        for (int h = 0; h < NH; ++h) logits[n][h] = 0.0f;

    #pragma unroll
    for (int pp = 0; pp < 6; ++pp) {
        const int d1 = 16 * pp + l;
        const float t1 = tqrow[d1];
        const float t2 = tqrow[d1 + 8];

        const float* r1 = kvS + d1 * 12;
        const float* r2 = kvS + (d1 + 8) * 12;
        const float4 ka1 = *(const float4*)(r1);
        const float4 kb1 = *(const float4*)(r1 + 4);
        const float2 kc1 = *(const float2*)(r1 + 8);
        const float4 ka2 = *(const float4*)(r2);
        const float4 kb2 = *(const float4*)(r2 + 4);
        const float2 kc2 = *(const float2*)(r2 + 8);
        const float kv1[NT] = {ka1.x, ka1.y, ka1.z, ka1.w, kb1.x, kb1.y, kb1.z, kb1.w, kc1.x, kc1.y};
        const float kv2[NT] = {ka2.x, ka2.y, ka2.z, ka2.w, kb2.x, kb2.y, kb2.z, kb2.w, kc2.x, kc2.y};

        const h2* wrow = &wvpS[(pp * 8 + l) * 4];
        const h2 w0 = wrow[0], w1 = wrow[1], w2 = wrow[2], w3 = wrow[3];

        #pragma unroll
        for (int n = 0; n < NT; ++n) {
            // s = tanh(q + k) via addition formula on pre-tanh'd values
            float s1 = (t1 + kv1[n]) * __builtin_amdgcn_rcpf(fmaf(t1, kv1[n], 1.0f));
            float s2 = (t2 + kv2[n]) * __builtin_amdgcn_rcpf(fmaf(t2, kv2[n], 1.0f));
            h2 sp = pack_h2(s1, s2);
            logits[n][0] = dot2acc(sp, w0, logits[n][0]);
            logits[n][1] = dot2acc(sp, w1, logits[n][1]);
            logits[n][2] = dot2acc(sp, w2, logits[n][2]);
            logits[n][3] = dot2acc(sp, w3, logits[n][3]);
        }
    }

    // ---- logits reduce-scatter: lane ends with lh[n] for head h = l&3 ----
    const bool myb0 = (l & 1) != 0;
    const bool myb1 = (l & 2) != 0;
    float lh[NT];
    #pragma unroll
    for (int n = 0; n < NT; ++n) {
        float L0 = logits[n][0], L1 = logits[n][1];
        float L2 = logits[n][2], L3 = logits[n][3];
        L0 += __shfl_xor(L0, 4);
        L1 += __shfl_xor(L1, 4);
        L2 += __shfl_xor(L2, 4);
        L3 += __shfl_xor(L3, 4);
        float m0 = myb1 ? L2 : L0, m1 = myb1 ? L3 : L1;
        float t0 = myb1 ? L0 : L2, t1 = myb1 ? L1 : L3;
        m0 += __shfl_xor(t0, 2);
        m1 += __shfl_xor(t1, 2);
        float mm = myb0 ? m1 : m0, tt = myb0 ? m0 : m1;
        lh[n] = mm + __shfl_xor(tt, 1);
    }

    // ---- per-lane softmax (head l&3); wn[n] = mean_h attn ----
    float m = lh[0];
    #pragma unroll
    for (int n = 1; n < NT; ++n) m = fmaxf(m, lh[n]);
    float e[NT];
    float ssum = 0.0f;
    #pragma unroll
    for (int n = 0; n < NT; ++n) {
        e[n] = __expf(lh[n] - m);
        ssum += e[n];
    }
    const float inv = 0.25f * __builtin_amdgcn_rcpf(ssum);
    float wn[NT];
    #pragma unroll
    for (int n = 0; n < NT; ++n) {
        float v = e[n] * inv;
        v += __shfl_xor(v, 1);
        v += __shfl_xor(v, 2);
        wn[n] = v;
    }

    // ---- style + store, coalesced: lane handles float4-index l + 8*jj ----
    float4* ob = (float4*)(out + (size_t)pos * TD);
    const float4* t4 = (const float4*)tokens;
    #pragma unroll
    for (int jj = 0; jj < 3; ++jj) {
        const int d4 = l + 8 * jj;
        float4 o = make_float4(0.f, 0.f, 0.f, 0.f);
        #pragma unroll
        for (int n = 0; n < NT; ++n) {
            float4 t = t4[n * (TD / 4) + d4];
            o.x = fmaf(wn[n], t.x, o.x);
            o.y = fmaf(wn[n], t.y, o.y);
            o.z = fmaf(wn[n], t.z, o.z);
            o.w = fmaf(wn[n], t.w, o.w);
        }
        ob[d4] = o;
    }
}

extern "C" void kernel_launch(void* const* d_in, const int* in_sizes, int n_in,
                              void* d_out, int out_size, void* d_ws, size_t ws_size,
                              hipStream_t stream) {
    const float* ref_emb = (const float*)d_in[0];
    const float* tokens  = (const float*)d_in[1];
    const float* Wq      = (const float*)d_in[2];
    const float* Wk      = (const float*)d_in[3];
    const float* Wv      = (const float*)d_in[4];
    float* out = (float*)d_out;

    gst_prep<<<48, 256, 0, stream>>>(tokens, Wq, Wk, Wv, (char*)d_ws);
    gst_main<<<NPOS / PPB, TPB, 0, stream>>>(ref_emb, tokens,
                                             (const char*)d_ws, out);
}

// Round 19
// 38.849 us; speedup vs baseline: 2.8036x; 1.0325x over previous
//
#include <hip/hip_runtime.h>
#include <rocwmma/rocwmma.hpp>
#include <cstddef>

#define NT 10            // NUM_TOKENS
#define TD 96            // TOKEN_DIM == REF_DIM
#define NH 4             // NUM_HEADS
#define NPOS (32 * 2048) // B*T positions
#define TPB 256
#define PPB 32           // positions per block; 8 lanes/pos in s-phase
#define LDQ 104          // padded f16 leading dim for xS and eqS

// workspace layout (bytes)
#define WS_WQ 0          // f16 wq16[96][96] row-major (18432 B) -> wmma B
#define WS_KV2 18432     // float Ek[96][12]: e^{2 tanh(tok.Wk)}, pad 2 (4608 B)
#define WS_WVP 23040     // h2 wvp[6][8][4]: (Wv[h][16pp+l], Wv[h][16pp+8+l]) (768 B)
#define WS_C 23808       // float C[4]: C[h] = sum_d Wv[h][d] (16 B)
#define WS_BYTES 23824

typedef _Float16 h2 __attribute__((ext_vector_type(2)));

__device__ __forceinline__ h2 pack_h2(float a, float b) {
    return __builtin_bit_cast(h2, __builtin_amdgcn_cvt_pkrtz(a, b));
}

__device__ __forceinline__ float fast_tanh(float x) {
    // tanh(x) = 1 - 2/(exp(2x)+1); exact limits at +/-inf, ~1e-6 rel error
    float e = __expf(2.0f * x);
    return 1.0f - 2.0f * __builtin_amdgcn_rcpf(e + 1.0f);
}

__device__ __forceinline__ float dot2acc(h2 a, h2 b, float c) {
#if __has_builtin(__builtin_amdgcn_fdot2)
    return __builtin_amdgcn_fdot2(a, b, c, false);
#else
    c = fmaf((float)a[0], (float)b[0], c);
    return fmaf((float)a[1], (float)b[1], c);
#endif
}

// ---- prep: 48 blocks; block b owns d-slice [2b, 2b+2); block 0 also wvp/C ----
__global__ __launch_bounds__(256) void gst_prep(
    const float* __restrict__ tokens,
    const float* __restrict__ Wq,
    const float* __restrict__ Wk,
    const float* __restrict__ Wv,
    char* __restrict__ ws)
{
    h2* wqH = (h2*)(ws + WS_WQ);
    float* kv2 = (float*)(ws + WS_KV2);
    h2* wvp = (h2*)(ws + WS_WVP);
    float* Cws = (float*)(ws + WS_C);
    const int b = blockIdx.x;
    const int tid = threadIdx.x;

    // Wq rows -> f16 (2 rows x 48 pairs); [96][48] h2 == [96][96] f16 row-major
    if (tid < 2 * (TD / 2)) {
        int r = 2 * b + tid / (TD / 2);
        int c = tid % (TD / 2);
        float2 f = ((const float2*)(Wq + r * TD))[c];
        wqH[r * (TD / 2) + c] = pack_h2(f.x, f.y);
    }
    // Ek[d][n] = exp(2 * tanh(tokens[n] . Wk[d]))   (exp-form of tanh addition)
    if (tid < 2 * NT) {
        int d = 2 * b + tid / NT;
        int n = tid % NT;
        const float4* tr = (const float4*)(tokens + n * TD);
        const float4* wr = (const float4*)(Wk + d * TD);
        float acc = 0.0f;
        #pragma unroll
        for (int j = 0; j < TD / 4; ++j) {
            float4 a = tr[j];
            float4 w = wr[j];
            acc = fmaf(a.x, w.x, acc);
            acc = fmaf(a.y, w.y, acc);
            acc = fmaf(a.z, w.z, acc);
            acc = fmaf(a.w, w.w, acc);
        }
        kv2[d * 12 + n] = __expf(2.0f * fast_tanh(acc));
    }
    if (tid < 2 * 2) { // zero the pad
        int d = 2 * b + (tid >> 1);
        kv2[d * 12 + 10 + (tid & 1)] = 0.0f;
    }
    // wvp pairs (block 0): 192 items
    if (b == 0 && tid < 192) {
        int pp = tid >> 5;
        int l = (tid >> 2) & 7;
        int h = tid & 3;
        wvp[(pp * 8 + l) * 4 + h] =
            pack_h2(Wv[h * TD + 16 * pp + l], Wv[h * TD + 16 * pp + 8 + l]);
    }
    // C[h] = sum_d Wv[h][d] (block 0, threads 224..227)
    if (b == 0 && tid >= 224 && tid < 224 + NH) {
        int h = tid - 224;
        float c = 0.0f;
        for (int d = 0; d < TD; ++d) c += Wv[h * TD + d];
        Cws[h] = c;
    }
}

// ---- main: rocWMMA q-projection -> Eq f16 in LDS -> exp-form s-phase ----
__global__ __launch_bounds__(TPB, 6) void gst_main(
    const float* __restrict__ ref_emb,
    const float* __restrict__ tokens,
    const char* __restrict__ ws,
    float* __restrict__ out)
{
    __shared__ __align__(16) _Float16 xS[PPB * LDQ];  // 6656 B
    __shared__ __align__(16) _Float16 eqS[PPB * LDQ]; // 6656 B: Eq = e^{2 tanh q}
    __shared__ __align__(16) float kvS[TD * 12];      // 4608 B: Ek
    __shared__ __align__(16) h2 wvpS[6 * 8 * 4];      //  768 B  (total 18688)

    const int tid = threadIdx.x;
    const int P0 = blockIdx.x * PPB;

    // ---- stage x -> LDS f16 + kv/wvp -> LDS, all upfront ----
    {
        const float4* src = (const float4*)(ref_emb + (size_t)P0 * TD);
        #pragma unroll
        for (int it = 0; it < 3; ++it) {
            int t = tid + it * TPB;
            int row = t / (TD / 4);
            int c4 = t - row * (TD / 4);
            float4 v = src[t];
            h2* dst = (h2*)(xS + row * LDQ + c4 * 4);
            dst[0] = pack_h2(v.x, v.y);
            dst[1] = pack_h2(v.z, v.w);
        }
        const float4* sKV = (const float4*)(ws + WS_KV2); // 288 float4
        float4* dKV = (float4*)kvS;
        dKV[tid % 288] = sKV[tid % 288]; // tid<256 covers 0..255
        if (tid < 32) dKV[256 + tid] = sKV[256 + tid];
        const float4* sWV = (const float4*)(ws + WS_WVP); // 48 float4
        float4* dWV = (float4*)wvpS;
        if (tid >= 64 && tid < 112) dWV[tid - 64] = sWV[tid - 64];
    }
    __syncthreads();

    // ---- MFMA q phase via rocWMMA; Eq stored f16 by hand (m89 acc mapping:
    //      x[e] -> row = 4*(lane>>4)+e, col = lane&15) ----
    {
        using namespace rocwmma;
        const int lane = tid & 63;
        const int wid = tid >> 6;
        const int ph = wid >> 1;
        const int dh = wid & 1;
        const int arow = lane & 15;
        const int kgrp = lane >> 4;

        fragment<matrix_a, 16, 16, 16, float16_t, row_major> fa[6];
        #pragma unroll
        for (int kb = 0; kb < 6; ++kb)
            load_matrix_sync(fa[kb],
                (const float16_t*)(xS + ph * 16 * LDQ + kb * 16), LDQ);

        const float16_t* wq16 = (const float16_t*)(ws + WS_WQ);
        fragment<accumulator, 16, 16, 16, float> fc[3];
        #pragma unroll
        for (int t = 0; t < 3; ++t) {
            fill_fragment(fc[t], 0.0f);
            #pragma unroll
            for (int kb = 0; kb < 6; ++kb) {
                fragment<matrix_b, 16, 16, 16, float16_t, col_major> fb;
                load_matrix_sync(fb, wq16 + (dh * 3 + t) * 16 * TD + kb * 16, TD);
                mma_sync(fc[t], fa[kb], fb, fc[t]);
            }
        }
        #pragma unroll
        for (int t = 0; t < 3; ++t) {
            const int d = dh * 48 + t * 16 + arow;
            #pragma unroll
            for (int e = 0; e < 4; ++e) {
                const int p = ph * 16 + kgrp * 4 + e;
                eqS[p * LDQ + d] = (_Float16)__expf(2.0f * fast_tanh(fc[t].x[e]));
            }
        }
    }
    __syncthreads();

    // ---- s-phase (exp form): 8 lanes/pos, lane owns d-pair {16pp+l, +8} ----
    const int prow = tid >> 3;
    const int pos = P0 + prow;
    const int l = tid & 7;
    const _Float16* eqrow = eqS + prow * LDQ;

    float R[NT][NH]; // R[n][h] = sum_d r(n,d) * wv(h,d); logit = C - 2R
    #pragma unroll
    for (int n = 0; n < NT; ++n)
        #pragma unroll
        for (int h = 0; h < NH; ++h) R[n][h] = 0.0f;

    #pragma unroll
    for (int pp = 0; pp < 6; ++pp) {
        const int d1 = 16 * pp + l;
        const float Eq1 = (float)eqrow[d1];
        const float Eq2 = (float)eqrow[d1 + 8];

        const float* r1 = kvS + d1 * 12;
        const float* r2 = kvS + (d1 + 8) * 12;
        const float4 ka1 = *(const float4*)(r1);
        const float4 kb1 = *(const float4*)(r1 + 4);
        const float2 kc1 = *(const float2*)(r1 + 8);
        const float4 ka2 = *(const float4*)(r2);
        const float4 kb2 = *(const float4*)(r2 + 4);
        const float2 kc2 = *(const float2*)(r2 + 8);
        const float ek1[NT] = {ka1.x, ka1.y, ka1.z, ka1.w, kb1.x, kb1.y, kb1.z, kb1.w, kc1.x, kc1.y};
        const float ek2[NT] = {ka2.x, ka2.y, ka2.z, ka2.w, kb2.x, kb2.y, kb2.z, kb2.w, kc2.x, kc2.y};

        const h2* wrow = &wvpS[(pp * 8 + l) * 4];
        const h2 w0 = wrow[0], w1 = wrow[1], w2 = wrow[2], w3 = wrow[3];

        #pragma unroll
        for (int n = 0; n < NT; ++n) {
            // r = 1/(Eq*Ek + 1); s = 1 - 2r (applied post-reduce via C[h])
            float v1 = __builtin_amdgcn_rcpf(fmaf(Eq1, ek1[n], 1.0f));
            float v2 = __builtin_amdgcn_rcpf(fmaf(Eq2, ek2[n], 1.0f));
            h2 rp = pack_h2(v1, v2);
            R[n][0] = dot2acc(rp, w0, R[n][0]);
            R[n][1] = dot2acc(rp, w1, R[n][1]);
            R[n][2] = dot2acc(rp, w2, R[n][2]);
            R[n][3] = dot2acc(rp, w3, R[n][3]);
        }
    }

    // ---- reduce-scatter R: lane ends with Rh[n] for head h = l&3 ----
    const bool myb0 = (l & 1) != 0;
    const bool myb1 = (l & 2) != 0;
    float lh[NT];
    #pragma unroll
    for (int n = 0; n < NT; ++n) {
        float L0 = R[n][0], L1 = R[n][1];
        float L2 = R[n][2], L3 = R[n][3];
        L0 += __shfl_xor(L0, 4);
        L1 += __shfl_xor(L1, 4);
        L2 += __shfl_xor(L2, 4);
        L3 += __shfl_xor(L3, 4);
        float m0 = myb1 ? L2 : L0, m1 = myb1 ? L3 : L1;
        float t0 = myb1 ? L0 : L2, t1 = myb1 ? L1 : L3;
        m0 += __shfl_xor(t0, 2);
        m1 += __shfl_xor(t1, 2);
        float mm = myb0 ? m1 : m0, tt = myb0 ? m0 : m1;
        lh[n] = mm + __shfl_xor(tt, 1);
    }

    // logits for this lane's head: lh[n] = C[h] - 2*Rh[n]
    {
        const float4 Call = *(const float4*)(ws + WS_C);
        const float Ch = myb0 ? (myb1 ? Call.w : Call.y)
                              : (myb1 ? Call.z : Call.x);
        #pragma unroll
        for (int n = 0; n < NT; ++n) lh[n] = fmaf(-2.0f, lh[n], Ch);
    }

    // ---- per-lane softmax (head l&3); wn[n] = mean_h attn ----
    float m = lh[0];
    #pragma unroll
    for (int n = 1; n < NT; ++n) m = fmaxf(m, lh[n]);
    float e[NT];
    float ssum = 0.0f;
    #pragma unroll
    for (int n = 0; n < NT; ++n) {
        e[n] = __expf(lh[n] - m);
        ssum += e[n];
    }
    const float inv = 0.25f * __builtin_amdgcn_rcpf(ssum);
    float wn[NT];
    #pragma unroll
    for (int n = 0; n < NT; ++n) {
        float v = e[n] * inv;
        v += __shfl_xor(v, 1);
        v += __shfl_xor(v, 2);
        wn[n] = v;
    }

    // ---- style + store, coalesced: lane handles float4-index l + 8*jj ----
    float4* ob = (float4*)(out + (size_t)pos * TD);
    const float4* t4 = (const float4*)tokens;
    #pragma unroll
    for (int jj = 0; jj < 3; ++jj) {
        const int d4 = l + 8 * jj;
        float4 o = make_float4(0.f, 0.f, 0.f, 0.f);
        #pragma unroll
        for (int n = 0; n < NT; ++n) {
            float4 t = t4[n * (TD / 4) + d4];
            o.x = fmaf(wn[n], t.x, o.x);
            o.y = fmaf(wn[n], t.y, o.y);
            o.z = fmaf(wn[n], t.z, o.z);
            o.w = fmaf(wn[n], t.w, o.w);
        }
        ob[d4] = o;
    }
}

extern "C" void kernel_launch(void* const* d_in, const int* in_sizes, int n_in,
                              void* d_out, int out_size, void* d_ws, size_t ws_size,
                              hipStream_t stream) {
    const float* ref_emb = (const float*)d_in[0];
    const float* tokens  = (const float*)d_in[1];
    const float* Wq      = (const float*)d_in[2];
    const float* Wk      = (const float*)d_in[3];
    const float* Wv      = (const float*)d_in[4];
    float* out = (float*)d_out;

    gst_prep<<<48, 256, 0, stream>>>(tokens, Wq, Wk, Wv, (char*)d_ws);
    gst_main<<<NPOS / PPB, TPB, 0, stream>>>(ref_emb, tokens,
                                             (const char*)d_ws, out);
}

// Round 20
// 36.119 us; speedup vs baseline: 3.0156x; 1.0756x over previous
//
#include <hip/hip_runtime.h>
#include <rocwmma/rocwmma.hpp>
#include <cstddef>

#define NT 10            // NUM_TOKENS
#define TD 96            // TOKEN_DIM == REF_DIM
#define NH 4             // NUM_HEADS
#define NPOS (32 * 2048) // B*T positions
#define TPB 256
#define PPB 32           // positions per block; 8 lanes/pos in s-phase
#define LDQ 104          // padded f16 leading dim for xS and eqS

// workspace layout (bytes)
#define WS_WQ 0          // f16 wq16[96][96] row-major (18432 B) -> wmma B
#define WS_KV2 18432     // float Ek[96][12]: e^{2 tanh(tok.Wk)}, pad 2 (4608 B)
#define WS_WVP 23040     // h2 wvp[6][8][4]: (Wv[h][16pp+l], Wv[h][16pp+8+l]) (768 B)
#define WS_C 23808       // float C[4]: C[h] = sum_d Wv[h][d] (16 B)
#define WS_BYTES 23824

typedef _Float16 h2 __attribute__((ext_vector_type(2)));

__device__ __forceinline__ h2 pack_h2(float a, float b) {
    return __builtin_bit_cast(h2, __builtin_amdgcn_cvt_pkrtz(a, b));
}

__device__ __forceinline__ float fast_tanh(float x) {
    // tanh(x) = 1 - 2/(exp(2x)+1); exact limits at +/-inf, ~1e-6 rel error
    float e = __expf(2.0f * x);
    return 1.0f - 2.0f * __builtin_amdgcn_rcpf(e + 1.0f);
}

__device__ __forceinline__ float dot2acc(h2 a, h2 b, float c) {
#if __has_builtin(__builtin_amdgcn_fdot2)
    return __builtin_amdgcn_fdot2(a, b, c, false);
#else
    c = fmaf((float)a[0], (float)b[0], c);
    return fmaf((float)a[1], (float)b[1], c);
#endif
}

// ---- prep: 48 blocks; block b owns d-slice [2b, 2b+2); block 0 also wvp/C ----
__global__ __launch_bounds__(256) void gst_prep(
    const float* __restrict__ tokens,
    const float* __restrict__ Wq,
    const float* __restrict__ Wk,
    const float* __restrict__ Wv,
    char* __restrict__ ws)
{
    h2* wqH = (h2*)(ws + WS_WQ);
    float* kv2 = (float*)(ws + WS_KV2);
    h2* wvp = (h2*)(ws + WS_WVP);
    float* Cws = (float*)(ws + WS_C);
    const int b = blockIdx.x;
    const int tid = threadIdx.x;

    // Wq rows -> f16 (2 rows x 48 pairs); [96][48] h2 == [96][96] f16 row-major
    if (tid < 2 * (TD / 2)) {
        int r = 2 * b + tid / (TD / 2);
        int c = tid % (TD / 2);
        float2 f = ((const float2*)(Wq + r * TD))[c];
        wqH[r * (TD / 2) + c] = pack_h2(f.x, f.y);
    }
    // Ek[d][n] = exp(2 * tanh(tokens[n] . Wk[d]))   (exp-form of tanh addition)
    if (tid < 2 * NT) {
        int d = 2 * b + tid / NT;
        int n = tid % NT;
        const float4* tr = (const float4*)(tokens + n * TD);
        const float4* wr = (const float4*)(Wk + d * TD);
        float acc = 0.0f;
        #pragma unroll
        for (int j = 0; j < TD / 4; ++j) {
            float4 a = tr[j];
            float4 w = wr[j];
            acc = fmaf(a.x, w.x, acc);
            acc = fmaf(a.y, w.y, acc);
            acc = fmaf(a.z, w.z, acc);
            acc = fmaf(a.w, w.w, acc);
        }
        kv2[d * 12 + n] = __expf(2.0f * fast_tanh(acc));
    }
    if (tid < 2 * 2) { // zero the pad
        int d = 2 * b + (tid >> 1);
        kv2[d * 12 + 10 + (tid & 1)] = 0.0f;
    }
    // wvp pairs (block 0): 192 items
    if (b == 0 && tid < 192) {
        int pp = tid >> 5;
        int l = (tid >> 2) & 7;
        int h = tid & 3;
        wvp[(pp * 8 + l) * 4 + h] =
            pack_h2(Wv[h * TD + 16 * pp + l], Wv[h * TD + 16 * pp + 8 + l]);
    }
    // C[h] = sum_d Wv[h][d] (block 0, threads 224..227)
    if (b == 0 && tid >= 224 && tid < 224 + NH) {
        int h = tid - 224;
        float c = 0.0f;
        for (int d = 0; d < TD; ++d) c += Wv[h * TD + d];
        Cws[h] = c;
    }
}

// ---- main: rocWMMA q-projection -> Eq f16; xS region reused for tokens so
//      the style phase reads LDS instead of hammering L1 ----
__global__ __launch_bounds__(TPB, 6) void gst_main(
    const float* __restrict__ ref_emb,
    const float* __restrict__ tokens,
    const char* __restrict__ ws,
    float* __restrict__ out)
{
    __shared__ __align__(16) _Float16 xS[PPB * LDQ];  // 6656 B; later tokS f32
    __shared__ __align__(16) _Float16 eqS[PPB * LDQ]; // 6656 B: Eq = e^{2 tanh q}
    __shared__ __align__(16) float kvS[TD * 12];      // 4608 B: Ek
    __shared__ __align__(16) h2 wvpS[6 * 8 * 4];      //  768 B  (total 18688)

    const int tid = threadIdx.x;
    const int P0 = blockIdx.x * PPB;

    // tokens -> registers early (written to LDS after the wmma A-frag loads)
    float4 tokReg;
    if (tid < NT * TD / 4) tokReg = ((const float4*)tokens)[tid];

    // ---- stage x -> LDS f16 + kv/wvp -> LDS, all upfront ----
    {
        const float4* src = (const float4*)(ref_emb + (size_t)P0 * TD);
        #pragma unroll
        for (int it = 0; it < 3; ++it) {
            int t = tid + it * TPB;
            int row = t / (TD / 4);
            int c4 = t - row * (TD / 4);
            float4 v = src[t];
            h2* dst = (h2*)(xS + row * LDQ + c4 * 4);
            dst[0] = pack_h2(v.x, v.y);
            dst[1] = pack_h2(v.z, v.w);
        }
        const float4* sKV = (const float4*)(ws + WS_KV2); // 288 float4
        float4* dKV = (float4*)kvS;
        dKV[tid] = sKV[tid];
        if (tid < 32) dKV[256 + tid] = sKV[256 + tid];
        const float4* sWV = (const float4*)(ws + WS_WVP); // 48 float4
        float4* dWV = (float4*)wvpS;
        if (tid >= 64 && tid < 112) dWV[tid - 64] = sWV[tid - 64];
    }
    __syncthreads();

    // ---- MFMA q phase via rocWMMA; Eq stored f16 by hand (m89 acc mapping:
    //      x[e] -> row = 4*(lane>>4)+e, col = lane&15) ----
    {
        using namespace rocwmma;
        const int lane = tid & 63;
        const int wid = tid >> 6;
        const int ph = wid >> 1;
        const int dh = wid & 1;
        const int arow = lane & 15;
        const int kgrp = lane >> 4;

        fragment<matrix_a, 16, 16, 16, float16_t, row_major> fa[6];
        #pragma unroll
        for (int kb = 0; kb < 6; ++kb)
            load_matrix_sync(fa[kb],
                (const float16_t*)(xS + ph * 16 * LDQ + kb * 16), LDQ);

        __syncthreads(); // all waves' A-frag loads done: xS is now dead

        // overwrite xS region with tokens (f32): style reads LDS, not L1
        if (tid < NT * TD / 4) ((float4*)xS)[tid] = tokReg;

        const float16_t* wq16 = (const float16_t*)(ws + WS_WQ);
        fragment<accumulator, 16, 16, 16, float> fc[3];
        #pragma unroll
        for (int t = 0; t < 3; ++t) {
            fill_fragment(fc[t], 0.0f);
            #pragma unroll
            for (int kb = 0; kb < 6; ++kb) {
                fragment<matrix_b, 16, 16, 16, float16_t, col_major> fb;
                load_matrix_sync(fb, wq16 + (dh * 3 + t) * 16 * TD + kb * 16, TD);
                mma_sync(fc[t], fa[kb], fb, fc[t]);
            }
        }
        #pragma unroll
        for (int t = 0; t < 3; ++t) {
            const int d = dh * 48 + t * 16 + arow;
            #pragma unroll
            for (int e = 0; e < 4; ++e) {
                const int p = ph * 16 + kgrp * 4 + e;
                eqS[p * LDQ + d] = (_Float16)__expf(2.0f * fast_tanh(fc[t].x[e]));
            }
        }
    }
    __syncthreads();

    const float* tokS = (const float*)xS; // [10][96] f32

    // ---- s-phase (exp form): 8 lanes/pos, lane owns d-pair {16pp+l, +8} ----
    const int prow = tid >> 3;
    const int pos = P0 + prow;
    const int l = tid & 7;
    const _Float16* eqrow = eqS + prow * LDQ;

    float R[NT][NH]; // R[n][h] = sum_d r(n,d) * wv(h,d); logit = C - 2R
    #pragma unroll
    for (int n = 0; n < NT; ++n)
        #pragma unroll
        for (int h = 0; h < NH; ++h) R[n][h] = 0.0f;

    #pragma unroll
    for (int pp = 0; pp < 6; ++pp) {
        const int d1 = 16 * pp + l;
        const float Eq1 = (float)eqrow[d1];
        const float Eq2 = (float)eqrow[d1 + 8];

        const float* r1 = kvS + d1 * 12;
        const float* r2 = kvS + (d1 + 8) * 12;
        const float4 ka1 = *(const float4*)(r1);
        const float4 kb1 = *(const float4*)(r1 + 4);
        const float2 kc1 = *(const float2*)(r1 + 8);
        const float4 ka2 = *(const float4*)(r2);
        const float4 kb2 = *(const float4*)(r2 + 4);
        const float2 kc2 = *(const float2*)(r2 + 8);
        const float ek1[NT] = {ka1.x, ka1.y, ka1.z, ka1.w, kb1.x, kb1.y, kb1.z, kb1.w, kc1.x, kc1.y};
        const float ek2[NT] = {ka2.x, ka2.y, ka2.z, ka2.w, kb2.x, kb2.y, kb2.z, kb2.w, kc2.x, kc2.y};

        const h2* wrow = &wvpS[(pp * 8 + l) * 4];
        const h2 w0 = wrow[0], w1 = wrow[1], w2 = wrow[2], w3 = wrow[3];

        #pragma unroll
        for (int n = 0; n < NT; ++n) {
            // r = 1/(Eq*Ek + 1); s = 1 - 2r (applied post-reduce via C[h])
            float v1 = __builtin_amdgcn_rcpf(fmaf(Eq1, ek1[n], 1.0f));
            float v2 = __builtin_amdgcn_rcpf(fmaf(Eq2, ek2[n], 1.0f));
            h2 rp = pack_h2(v1, v2);
            R[n][0] = dot2acc(rp, w0, R[n][0]);
            R[n][1] = dot2acc(rp, w1, R[n][1]);
            R[n][2] = dot2acc(rp, w2, R[n][2]);
            R[n][3] = dot2acc(rp, w3, R[n][3]);
        }
    }

    // ---- reduce-scatter R: lane ends with Rh[n] for head h = l&3 ----
    const bool myb0 = (l & 1) != 0;
    const bool myb1 = (l & 2) != 0;
    float lh[NT];
    #pragma unroll
    for (int n = 0; n < NT; ++n) {
        float L0 = R[n][0], L1 = R[n][1];
        float L2 = R[n][2], L3 = R[n][3];
        L0 += __shfl_xor(L0, 4);
        L1 += __shfl_xor(L1, 4);
        L2 += __shfl_xor(L2, 4);
        L3 += __shfl_xor(L3, 4);
        float m0 = myb1 ? L2 : L0, m1 = myb1 ? L3 : L1;
        float t0 = myb1 ? L0 : L2, t1 = myb1 ? L1 : L3;
        m0 += __shfl_xor(t0, 2);
        m1 += __shfl_xor(t1, 2);
        float mm = myb0 ? m1 : m0, tt = myb0 ? m0 : m1;
        lh[n] = mm + __shfl_xor(tt, 1);
    }

    // logits for this lane's head: lh[n] = C[h] - 2*Rh[n]
    {
        const float4 Call = *(const float4*)(ws + WS_C);
        const float Ch = myb0 ? (myb1 ? Call.w : Call.y)
                              : (myb1 ? Call.z : Call.x);
        #pragma unroll
        for (int n = 0; n < NT; ++n) lh[n] = fmaf(-2.0f, lh[n], Ch);
    }

    // ---- per-lane softmax (head l&3); wn[n] = mean_h attn ----
    float m = lh[0];
    #pragma unroll
    for (int n = 1; n < NT; ++n) m = fmaxf(m, lh[n]);
    float e[NT];
    float ssum = 0.0f;
    #pragma unroll
    for (int n = 0; n < NT; ++n) {
        e[n] = __expf(lh[n] - m);
        ssum += e[n];
    }
    const float inv = 0.25f * __builtin_amdgcn_rcpf(ssum);
    float wn[NT];
    #pragma unroll
    for (int n = 0; n < NT; ++n) {
        float v = e[n] * inv;
        v += __shfl_xor(v, 1);
        v += __shfl_xor(v, 2);
        wn[n] = v;
    }

    // ---- style + store; tokens from LDS (banks 4l..4l+3, conflict-free) ----
    float4* ob = (float4*)(out + (size_t)pos * TD);
    const float4* t4 = (const float4*)tokS;
    #pragma unroll
    for (int jj = 0; jj < 3; ++jj) {
        const int d4 = l + 8 * jj;
        float4 o = make_float4(0.f, 0.f, 0.f, 0.f);
        #pragma unroll
        for (int n = 0; n < NT; ++n) {
            float4 t = t4[n * (TD / 4) + d4];
            o.x = fmaf(wn[n], t.x, o.x);
            o.y = fmaf(wn[n], t.y, o.y);
            o.z = fmaf(wn[n], t.z, o.z);
            o.w = fmaf(wn[n], t.w, o.w);
        }
        ob[d4] = o;
    }
}

extern "C" void kernel_launch(void* const* d_in, const int* in_sizes, int n_in,
                              void* d_out, int out_size, void* d_ws, size_t ws_size,
                              hipStream_t stream) {
    const float* ref_emb = (const float*)d_in[0];
    const float* tokens  = (const float*)d_in[1];
    const float* Wq      = (const float*)d_in[2];
    const float* Wk      = (const float*)d_in[3];
    const float* Wv      = (const float*)d_in[4];
    float* out = (float*)d_out;

    gst_prep<<<48, 256, 0, stream>>>(tokens, Wq, Wk, Wv, (char*)d_ws);
    gst_main<<<NPOS / PPB, TPB, 0, stream>>>(ref_emb, tokens,
                                             (const char*)d_ws, out);
}